// Round 1
// baseline (771.060 us; speedup 1.0000x reference)
//
#include <hip/hip_runtime.h>

#define N_NODES  50000
#define N_EDGES  1600000
#define N_GRAPHS 2048
#define DIM      133
#define DPAD     136
#define EPSV     1e-5f

// ---------------- setup kernels ----------------

__global__ __launch_bounds__(256) void k_count(const int* __restrict__ col,
                                               const int* __restrict__ batch,
                                               int* __restrict__ deg,
                                               int* __restrict__ cnt)
{
    int idx = blockIdx.x * 256 + threadIdx.x;
    if (idx < N_EDGES) atomicAdd(&deg[col[idx]], 1);
    if (idx < N_NODES) atomicAdd(&cnt[batch[idx]], 1);
}

__global__ __launch_bounds__(256) void k_finalize(const int* __restrict__ deg,
                                                  const int* __restrict__ cnt,
                                                  float* __restrict__ dinv,
                                                  float* __restrict__ inv_cnt)
{
    int idx = blockIdx.x * 256 + threadIdx.x;
    if (idx < N_NODES)  dinv[idx]    = rsqrtf((float)deg[idx] + 1.0f); // +1 self loop
    if (idx < N_GRAPHS) inv_cnt[idx] = 1.0f / (float)max(cnt[idx], 1);
}

__global__ __launch_bounds__(256) void k_scan1(const int* __restrict__ deg,
                                               int* __restrict__ offs,
                                               int* __restrict__ bsum)
{
    __shared__ int sd[256];
    int t = threadIdx.x;
    int idx = blockIdx.x * 256 + t;
    int v = (idx < N_NODES) ? deg[idx] : 0;
    sd[t] = v; __syncthreads();
    for (int o = 1; o < 256; o <<= 1) {
        int add = (t >= o) ? sd[t - o] : 0;
        __syncthreads();
        sd[t] += add;
        __syncthreads();
    }
    if (idx < N_NODES) offs[idx] = sd[t] - v;     // exclusive within block
    if (t == 255) bsum[blockIdx.x] = sd[255];     // block total
}

__global__ __launch_bounds__(256) void k_scan2(const int* __restrict__ bsum,
                                               int* __restrict__ boff, int nb)
{
    __shared__ int sd[256];
    int t = threadIdx.x;
    int v = (t < nb) ? bsum[t] : 0;
    sd[t] = v; __syncthreads();
    for (int o = 1; o < 256; o <<= 1) {
        int add = (t >= o) ? sd[t - o] : 0;
        __syncthreads();
        sd[t] += add;
        __syncthreads();
    }
    boff[t] = sd[t] - v;                          // exclusive block offsets
}

__global__ __launch_bounds__(256) void k_scan3(int* __restrict__ offs,
                                               const int* __restrict__ boff)
{
    int idx = blockIdx.x * 256 + threadIdx.x;
    if (idx < N_NODES)       offs[idx] += boff[blockIdx.x];
    else if (idx == N_NODES) offs[N_NODES] = N_EDGES;
}

__global__ __launch_bounds__(256) void k_fill(const int* __restrict__ row,
                                              const int* __restrict__ col,
                                              const int* __restrict__ offs,
                                              int* __restrict__ cursor,
                                              const float* __restrict__ dinv,
                                              int* __restrict__ csr_src,
                                              float* __restrict__ csr_w)
{
    int e = blockIdx.x * 256 + threadIdx.x;
    if (e < N_EDGES) {
        int c = col[e];
        int p = offs[c] + atomicAdd(&cursor[c], 1);
        int r = row[e];
        csr_src[p] = r;
        csr_w[p]   = dinv[r];
    }
}

// ---------------- dense GEMM: H[M][DPAD] = A[M][lda(=133|136)] @ W[133][133] ----------------

__global__ __launch_bounds__(256, 2) void k_gemm(const float* __restrict__ A, int lda,
                                                 const float* __restrict__ W,
                                                 float* __restrict__ H, int M)
{
    __shared__ float xs[64][137];   // +pad: 16 rows/wave hit 16 distinct banks
    __shared__ float wsh[48][144];  // 144 keeps per-thread 36-col segments float4-aligned
    int t = threadIdx.x;
    int rowBase = blockIdx.x * 64;

    for (int idx = t; idx < 64 * DIM; idx += 256) {
        int r = idx / DIM, c = idx - r * DIM;
        int gr = rowBase + r;
        xs[r][c] = (gr < M) ? A[(size_t)gr * lda + c] : 0.f;
    }

    int r = t >> 2, cq = t & 3, c0 = cq * 36;
    float4 acc[9];
#pragma unroll
    for (int j = 0; j < 9; j++) acc[j] = make_float4(0.f, 0.f, 0.f, 0.f);

    for (int k0 = 0; k0 < DIM; k0 += 48) {
        int KC = min(48, DIM - k0);
        __syncthreads();
        for (int idx = t; idx < KC * DIM; idx += 256) {
            int kk = idx / DIM, c = idx - kk * DIM;
            wsh[kk][c] = W[(size_t)(k0 + kk) * DIM + c];
        }
        __syncthreads();
        for (int kk = 0; kk < KC; kk++) {
            float xv = xs[r][k0 + kk];
            const float4* wrow = (const float4*)&wsh[kk][c0];
#pragma unroll
            for (int j = 0; j < 9; j++) {
                float4 wv = wrow[j];
                acc[j].x += xv * wv.x; acc[j].y += xv * wv.y;
                acc[j].z += xv * wv.z; acc[j].w += xv * wv.w;
            }
        }
    }

    int gr = rowBase + r;
    if (gr < M) {
        float* Hr = H + (size_t)gr * DPAD;
#pragma unroll
        for (int j = 0; j < 9; j++) {
            int c = c0 + 4 * j;
            if (c >= DPAD) break;
            if (c + 3 < DIM) {
                *(float4*)(Hr + c) = acc[j];
            } else {
                float vals[4] = {acc[j].x, acc[j].y, acc[j].z, acc[j].w};
#pragma unroll
                for (int e2 = 0; e2 < 4; e2++) {
                    int cc = c + e2;
                    if (cc < DIM)       Hr[cc] = vals[e2];
                    else if (cc < DPAD) Hr[cc] = 0.f;   // zero pad cols 133..135
                }
            }
        }
    }
}

// ---------------- fused aggregate + bias + ReLU + BN (+ optional mean-pool) ----------------
// out[i] = BN(relu(dinv[i]*(sum_e dinv[src]*h[src] + dinv[i]*h[i]) + b))

template <bool FINAL>
__global__ __launch_bounds__(256) void k_agg(const float* __restrict__ h,
                                             const int* __restrict__ offs,
                                             const int* __restrict__ csr_src,
                                             const float* __restrict__ csr_w,
                                             const float* __restrict__ dinv,
                                             const float* __restrict__ bias,
                                             const float* __restrict__ gam,
                                             const float* __restrict__ bet,
                                             const float* __restrict__ rmean,
                                             const float* __restrict__ rvar,
                                             float* __restrict__ y,
                                             const int* __restrict__ batch,
                                             const float* __restrict__ inv_cnt,
                                             float* __restrict__ outp)
{
    int node = blockIdx.x * 4 + (threadIdx.x >> 6);
    if (node >= N_NODES) return;
    int lane = threadIdx.x & 63;
    int l2 = lane & 3;

    float di = dinv[node];
    const float2* hrow = (const float2*)(h + (size_t)node * DPAD);
    float2 v0 = hrow[lane];          // cols 2*lane, 2*lane+1
    float2 v1 = hrow[64 + l2];       // cols 128+2*l2 (dup for lanes>=4, discarded)
    float2 a0; a0.x = di * v0.x; a0.y = di * v0.y;   // self-loop term
    float2 a1; a1.x = di * v1.x; a1.y = di * v1.y;

    int s0 = offs[node], s1 = offs[node + 1];
    for (int k0 = s0; k0 < s1; k0 += 64) {
        int nk = min(64, s1 - k0);
        int src = 0; float w = 0.f;
        if (lane < nk) { src = csr_src[k0 + lane]; w = csr_w[k0 + lane]; }
        for (int j = 0; j < nk; j++) {
            int   s  = __shfl(src, j);
            float ww = __shfl(w, j);
            const float2* hr = (const float2*)(h + (size_t)s * DPAD);
            float2 u0 = hr[lane];
            float2 u1 = hr[64 + l2];
            a0.x += ww * u0.x; a0.y += ww * u0.y;
            a1.x += ww * u1.x; a1.y += ww * u1.y;
        }
    }

    float ic = 0.f; int bg = 0;
    if (FINAL) { bg = batch[node]; ic = inv_cnt[bg]; }

    int c0 = 2 * lane;
    float av[4] = {a0.x, a0.y, a1.x, a1.y};
    int   cs[4] = {c0, c0 + 1, 128 + 2 * l2, 129 + 2 * l2};
    bool  wr[4] = {true, true, lane < 4, lane < 4};
#pragma unroll
    for (int q = 0; q < 4; q++) {
        int c = cs[q];
        if (wr[q] && c < DIM) {
            float val = di * av[q] + bias[c];
            val = fmaxf(val, 0.f);
            float sc = gam[c] * rsqrtf(rvar[c] + EPSV);
            val = (val - rmean[c]) * sc + bet[c];
            if (FINAL) atomicAdd(&outp[(size_t)bg * DIM + c], val * ic);
            else       y[(size_t)node * DPAD + c] = val;
        }
    }
}

// ---------------- launch ----------------

extern "C" void kernel_launch(void* const* d_in, const int* in_sizes, int n_in,
                              void* d_out, int out_size, void* d_ws, size_t ws_size,
                              hipStream_t stream)
{
    const float* x   = (const float*)d_in[0];
    const int*   ei  = (const int*)d_in[1];
    const int*   bat = (const int*)d_in[2];
    const float* W1  = (const float*)d_in[3];
    const float* b1  = (const float*)d_in[4];
    const float* W2  = (const float*)d_in[5];
    const float* b2  = (const float*)d_in[6];
    const float* g1  = (const float*)d_in[7];
    const float* be1 = (const float*)d_in[8];
    const float* rm1 = (const float*)d_in[9];
    const float* rv1 = (const float*)d_in[10];
    const float* g2  = (const float*)d_in[11];
    const float* be2 = (const float*)d_in[12];
    const float* rm2 = (const float*)d_in[13];
    const float* rv2 = (const float*)d_in[14];
    float* outp = (float*)d_out;
    char* ws = (char*)d_ws;

    int*   deg     = (int*)  (ws + 0);         // 200000 B
    int*   cursor  = (int*)  (ws + 200000);    // 200000 B
    int*   cnt     = (int*)  (ws + 400000);    //   8192 B
    int*   offs    = (int*)  (ws + 408192);    // 200016 B (N+1 ints)
    float* dinv    = (float*)(ws + 608208);    // 200000 B
    float* inv_cnt = (float*)(ws + 808208);    //   8192 B
    int*   bsum    = (int*)  (ws + 816400);    //   1024 B
    int*   boff    = (int*)  (ws + 817424);    //   1024 B
    int*   csr_src = (int*)  (ws + 818448);    // 6400000 B
    float* csr_w   = (float*)(ws + 7218448);   // 6400000 B
    float* bufA    = (float*)(ws + 13618448);  // 27200000 B (50000 x 136)
    float* bufB    = (float*)(ws + 40818448);  // 27200000 B

    hipMemsetAsync(ws, 0, 408192, stream);                       // deg, cursor, cnt
    hipMemsetAsync(d_out, 0, (size_t)out_size * 4, stream);

    const int* row = ei;
    const int* col = ei + N_EDGES;

    int ebl = (N_EDGES + 255) / 256;
    int nbl = (N_NODES + 255) / 256;

    k_count   <<<dim3(ebl), dim3(256), 0, stream>>>(col, bat, deg, cnt);
    k_finalize<<<dim3(nbl), dim3(256), 0, stream>>>(deg, cnt, dinv, inv_cnt);
    k_scan1   <<<dim3(nbl), dim3(256), 0, stream>>>(deg, offs, bsum);
    k_scan2   <<<dim3(1),   dim3(256), 0, stream>>>(bsum, boff, nbl);
    k_scan3   <<<dim3(nbl), dim3(256), 0, stream>>>(offs, boff);
    k_fill    <<<dim3(ebl), dim3(256), 0, stream>>>(row, col, offs, cursor, dinv, csr_src, csr_w);

    int gbl = (N_NODES + 63) / 64;
    k_gemm<<<dim3(gbl), dim3(256), 0, stream>>>(x, DIM, W1, bufA, N_NODES);
    k_agg<false><<<dim3(N_NODES / 4), dim3(256), 0, stream>>>(bufA, offs, csr_src, csr_w, dinv,
                                                              b1, g1, be1, rm1, rv1,
                                                              bufB, nullptr, nullptr, nullptr);
    k_gemm<<<dim3(gbl), dim3(256), 0, stream>>>(bufB, DPAD, W2, bufA, N_NODES);
    k_agg<true><<<dim3(N_NODES / 4), dim3(256), 0, stream>>>(bufA, offs, csr_src, csr_w, dinv,
                                                             b2, g2, be2, rm2, rv2,
                                                             nullptr, bat, inv_cnt, outp);
}

// Round 2
// 715.997 us; speedup vs baseline: 1.0769x; 1.0769x over previous
//
#include <hip/hip_runtime.h>

#define N_NODES  50000
#define N_EDGES  1600000
#define N_GRAPHS 2048
#define DIM      133
#define DPAD     136          // bf16 elements per row (272 B, 16B-aligned rows)
#define EPSV     1e-5f

// ---- bf16 helpers (raw ushort; OCP bf16 = top 16 bits of fp32) ----
__device__ __forceinline__ float blo(unsigned u) { return __uint_as_float(u << 16); }
__device__ __forceinline__ float bhi(unsigned u) { return __uint_as_float(u & 0xFFFF0000u); }
__device__ __forceinline__ unsigned short f2bf(float x) {
    unsigned v = __float_as_uint(x);
    return (unsigned short)((v + 0x7FFFu + ((v >> 16) & 1u)) >> 16);  // RNE
}
__device__ __forceinline__ unsigned packbf(float a, float b) {
    return (unsigned)f2bf(a) | ((unsigned)f2bf(b) << 16);
}

// ---------------- setup kernels ----------------

__global__ __launch_bounds__(256) void k_count(const int* __restrict__ col,
                                               const int* __restrict__ batch,
                                               int* __restrict__ deg,
                                               int* __restrict__ cnt)
{
    int idx = blockIdx.x * 256 + threadIdx.x;
    if (idx < N_EDGES) atomicAdd(&deg[col[idx]], 1);
    if (idx < N_NODES) atomicAdd(&cnt[batch[idx]], 1);
}

__global__ __launch_bounds__(256) void k_finalize(const int* __restrict__ deg,
                                                  const int* __restrict__ cnt,
                                                  float* __restrict__ dinv,
                                                  float* __restrict__ inv_cnt)
{
    int idx = blockIdx.x * 256 + threadIdx.x;
    if (idx < N_NODES)  dinv[idx]    = rsqrtf((float)deg[idx] + 1.0f); // +1 self loop
    if (idx < N_GRAPHS) inv_cnt[idx] = 1.0f / (float)max(cnt[idx], 1);
}

__global__ __launch_bounds__(256) void k_scan1(const int* __restrict__ deg,
                                               int* __restrict__ offs,
                                               int* __restrict__ bsum)
{
    __shared__ int sd[256];
    int t = threadIdx.x;
    int idx = blockIdx.x * 256 + t;
    int v = (idx < N_NODES) ? deg[idx] : 0;
    sd[t] = v; __syncthreads();
    for (int o = 1; o < 256; o <<= 1) {
        int add = (t >= o) ? sd[t - o] : 0;
        __syncthreads();
        sd[t] += add;
        __syncthreads();
    }
    if (idx < N_NODES) offs[idx] = sd[t] - v;
    if (t == 255) bsum[blockIdx.x] = sd[255];
}

__global__ __launch_bounds__(256) void k_scan2(const int* __restrict__ bsum,
                                               int* __restrict__ boff, int nb)
{
    __shared__ int sd[256];
    int t = threadIdx.x;
    int v = (t < nb) ? bsum[t] : 0;
    sd[t] = v; __syncthreads();
    for (int o = 1; o < 256; o <<= 1) {
        int add = (t >= o) ? sd[t - o] : 0;
        __syncthreads();
        sd[t] += add;
        __syncthreads();
    }
    boff[t] = sd[t] - v;
}

__global__ __launch_bounds__(256) void k_scan3(int* __restrict__ offs,
                                               const int* __restrict__ boff)
{
    int idx = blockIdx.x * 256 + threadIdx.x;
    if (idx < N_NODES)       offs[idx] += boff[blockIdx.x];
    else if (idx == N_NODES) offs[N_NODES] = N_EDGES;
}

__global__ __launch_bounds__(256) void k_fill(const int* __restrict__ row,
                                              const int* __restrict__ col,
                                              const int* __restrict__ offs,
                                              int* __restrict__ cursor,
                                              const float* __restrict__ dinv,
                                              int* __restrict__ csr_src,
                                              float* __restrict__ csr_w)
{
    int e = blockIdx.x * 256 + threadIdx.x;
    if (e < N_EDGES) {
        int c = col[e];
        int p = offs[c] + atomicAdd(&cursor[c], 1);
        int r = row[e];
        csr_src[p] = r;
        csr_w[p]   = dinv[r];
    }
}

// ---------------- dense GEMM: H[M][DPAD](bf16) = A[M][lda] @ W[133][133] ----------------
// fp32 accumulation; A is fp32 (layer 1) or bf16 (layer 2); output stored bf16.

template <typename TIN>
__global__ __launch_bounds__(256, 2) void k_gemm(const TIN* __restrict__ A, int lda,
                                                 const float* __restrict__ W,
                                                 unsigned short* __restrict__ H, int M)
{
    __shared__ float xs[64][137];
    __shared__ float wsh[48][144];
    int t = threadIdx.x;
    int rowBase = blockIdx.x * 64;

    for (int idx = t; idx < 64 * DIM; idx += 256) {
        int r = idx / DIM, c = idx - r * DIM;
        int gr = rowBase + r;
        float v = 0.f;
        if (gr < M) {
            TIN raw = A[(size_t)gr * lda + c];
            if constexpr (sizeof(TIN) == 2) v = __uint_as_float((unsigned)raw << 16);
            else                            v = (float)raw;
        }
        xs[r][c] = v;
    }

    int r = t >> 2, cq = t & 3, c0 = cq * 36;
    float4 acc[9];
#pragma unroll
    for (int j = 0; j < 9; j++) acc[j] = make_float4(0.f, 0.f, 0.f, 0.f);

    for (int k0 = 0; k0 < DIM; k0 += 48) {
        int KC = min(48, DIM - k0);
        __syncthreads();
        for (int idx = t; idx < KC * DIM; idx += 256) {
            int kk = idx / DIM, c = idx - kk * DIM;
            wsh[kk][c] = W[(size_t)(k0 + kk) * DIM + c];
        }
        __syncthreads();
        for (int kk = 0; kk < KC; kk++) {
            float xv = xs[r][k0 + kk];
            const float4* wrow = (const float4*)&wsh[kk][c0];
#pragma unroll
            for (int j = 0; j < 9; j++) {
                float4 wv = wrow[j];
                acc[j].x += xv * wv.x; acc[j].y += xv * wv.y;
                acc[j].z += xv * wv.z; acc[j].w += xv * wv.w;
            }
        }
    }

    int gr = rowBase + r;
    if (gr < M) {
        unsigned short* Hr = H + (size_t)gr * DPAD;
#pragma unroll
        for (int j = 0; j < 9; j++) {
            int c = c0 + 4 * j;
            if (c >= DPAD) break;
            float v0 = (c + 0 < DIM) ? acc[j].x : 0.f;
            float v1 = (c + 1 < DIM) ? acc[j].y : 0.f;
            float v2 = (c + 2 < DIM) ? acc[j].z : 0.f;
            float v3 = (c + 3 < DIM) ? acc[j].w : 0.f;
            uint2 u;
            u.x = packbf(v0, v1);
            u.y = packbf(v2, v3);
            *(uint2*)(Hr + c) = u;   // 8B-aligned: gr*272 + 2c, c%4==0
        }
    }
}

// ---------------- fused aggregate + bias + ReLU + BN (+ optional mean-pool) ----------------
// out[i] = BN(relu(dinv[i]*(sum_e dinv[src]*h[src] + dinv[i]*h[i]) + b))
// h is bf16 with row stride DPAD; one wave per destination node.

template <bool FINAL>
__global__ __launch_bounds__(256) void k_agg(const unsigned short* __restrict__ h,
                                             const int* __restrict__ offs,
                                             const int* __restrict__ csr_src,
                                             const float* __restrict__ csr_w,
                                             const float* __restrict__ dinv,
                                             const float* __restrict__ bias,
                                             const float* __restrict__ gam,
                                             const float* __restrict__ bet,
                                             const float* __restrict__ rmean,
                                             const float* __restrict__ rvar,
                                             unsigned short* __restrict__ y,
                                             const int* __restrict__ batch,
                                             const float* __restrict__ inv_cnt,
                                             float* __restrict__ outp)
{
    int node = blockIdx.x * 4 + (threadIdx.x >> 6);
    if (node >= N_NODES) return;
    int lane = threadIdx.x & 63;
    int l2 = lane & 3;

    float di = dinv[node];
    const unsigned* hrow = (const unsigned*)(h + (size_t)node * DPAD);
    unsigned p0 = hrow[lane];        // cols 2*lane, 2*lane+1
    unsigned p1 = hrow[64 + l2];     // cols 128+2*l2 (dup for lanes>=4, discarded)
    float2 a0; a0.x = di * blo(p0); a0.y = di * bhi(p0);   // self-loop term
    float2 a1; a1.x = di * blo(p1); a1.y = di * bhi(p1);

    int s0 = offs[node], s1 = offs[node + 1];
    for (int k0 = s0; k0 < s1; k0 += 64) {
        int nk = min(64, s1 - k0);
        int src = 0; float w = 0.f;
        if (lane < nk) { src = csr_src[k0 + lane]; w = csr_w[k0 + lane]; }
        for (int j = 0; j < nk; j++) {
            int   s  = __shfl(src, j);
            float ww = __shfl(w, j);
            const unsigned* hr = (const unsigned*)(h + (size_t)s * DPAD);
            unsigned q0 = hr[lane];
            unsigned q1 = hr[64 + l2];
            a0.x += ww * blo(q0); a0.y += ww * bhi(q0);
            a1.x += ww * blo(q1); a1.y += ww * bhi(q1);
        }
    }

    float ic = 0.f; int bg = 0;
    if (FINAL) { bg = batch[node]; ic = inv_cnt[bg]; }

    // main pair: cols 2*lane, 2*lane+1 (both < 128 < DIM)
    {
        int c = 2 * lane;
        float va = di * a0.x + bias[c];
        va = fmaxf(va, 0.f);
        va = (va - rmean[c]) * (gam[c] * rsqrtf(rvar[c] + EPSV)) + bet[c];
        int c1 = c + 1;
        float vb = di * a0.y + bias[c1];
        vb = fmaxf(vb, 0.f);
        vb = (vb - rmean[c1]) * (gam[c1] * rsqrtf(rvar[c1] + EPSV)) + bet[c1];
        if (FINAL) {
            atomicAdd(&outp[(size_t)bg * DIM + c],  va * ic);
            atomicAdd(&outp[(size_t)bg * DIM + c1], vb * ic);
        } else {
            ((unsigned*)((unsigned short*)y + (size_t)node * DPAD))[lane] = packbf(va, vb);
        }
    }
    // tail pair: cols 128+2*l2, 129+2*l2 (lanes 0..3 only)
    if (lane < 4) {
        int c = 128 + 2 * l2;
        float va = 0.f, vb = 0.f;
        if (c < DIM) {
            va = di * a1.x + bias[c];
            va = fmaxf(va, 0.f);
            va = (va - rmean[c]) * (gam[c] * rsqrtf(rvar[c] + EPSV)) + bet[c];
        }
        int c1 = c + 1;
        if (c1 < DIM) {
            vb = di * a1.y + bias[c1];
            vb = fmaxf(vb, 0.f);
            vb = (vb - rmean[c1]) * (gam[c1] * rsqrtf(rvar[c1] + EPSV)) + bet[c1];
        }
        if (FINAL) {
            if (c  < DIM) atomicAdd(&outp[(size_t)bg * DIM + c],  va * ic);
            if (c1 < DIM) atomicAdd(&outp[(size_t)bg * DIM + c1], vb * ic);
        } else {
            ((unsigned*)((unsigned short*)y + (size_t)node * DPAD))[64 + l2] = packbf(va, vb);
        }
    }
}

// ---------------- launch ----------------

extern "C" void kernel_launch(void* const* d_in, const int* in_sizes, int n_in,
                              void* d_out, int out_size, void* d_ws, size_t ws_size,
                              hipStream_t stream)
{
    const float* x   = (const float*)d_in[0];
    const int*   ei  = (const int*)d_in[1];
    const int*   bat = (const int*)d_in[2];
    const float* W1  = (const float*)d_in[3];
    const float* b1  = (const float*)d_in[4];
    const float* W2  = (const float*)d_in[5];
    const float* b2  = (const float*)d_in[6];
    const float* g1  = (const float*)d_in[7];
    const float* be1 = (const float*)d_in[8];
    const float* rm1 = (const float*)d_in[9];
    const float* rv1 = (const float*)d_in[10];
    const float* g2  = (const float*)d_in[11];
    const float* be2 = (const float*)d_in[12];
    const float* rm2 = (const float*)d_in[13];
    const float* rv2 = (const float*)d_in[14];
    float* outp = (float*)d_out;
    char* ws = (char*)d_ws;

    int*   deg     = (int*)  (ws + 0);         // 200000 B
    int*   cursor  = (int*)  (ws + 200000);    // 200000 B
    int*   cnt     = (int*)  (ws + 400000);    //   8192 B
    int*   offs    = (int*)  (ws + 408192);    // 200016 B (N+1 ints)
    float* dinv    = (float*)(ws + 608208);    // 200000 B
    float* inv_cnt = (float*)(ws + 808208);    //   8192 B
    int*   bsum    = (int*)  (ws + 816400);    //   1024 B
    int*   boff    = (int*)  (ws + 817424);    //   1024 B
    int*   csr_src = (int*)  (ws + 818448);    // 6400000 B
    float* csr_w   = (float*)(ws + 7218448);   // 6400000 B
    unsigned short* bufA = (unsigned short*)(ws + 13618448); // 13.6 MB (50000 x 136 bf16)
    unsigned short* bufB = (unsigned short*)(ws + 27218448); // 13.6 MB

    hipMemsetAsync(ws, 0, 408192, stream);                       // deg, cursor, cnt
    hipMemsetAsync(d_out, 0, (size_t)out_size * 4, stream);

    const int* row = ei;
    const int* col = ei + N_EDGES;

    int ebl = (N_EDGES + 255) / 256;
    int nbl = (N_NODES + 255) / 256;

    k_count   <<<dim3(ebl), dim3(256), 0, stream>>>(col, bat, deg, cnt);
    k_finalize<<<dim3(nbl), dim3(256), 0, stream>>>(deg, cnt, dinv, inv_cnt);
    k_scan1   <<<dim3(nbl), dim3(256), 0, stream>>>(deg, offs, bsum);
    k_scan2   <<<dim3(1),   dim3(256), 0, stream>>>(bsum, boff, nbl);
    k_scan3   <<<dim3(nbl), dim3(256), 0, stream>>>(offs, boff);
    k_fill    <<<dim3(ebl), dim3(256), 0, stream>>>(row, col, offs, cursor, dinv, csr_src, csr_w);

    int gbl = (N_NODES + 63) / 64;
    k_gemm<float><<<dim3(gbl), dim3(256), 0, stream>>>(x, DIM, W1, bufA, N_NODES);
    k_agg<false><<<dim3(N_NODES / 4), dim3(256), 0, stream>>>(bufA, offs, csr_src, csr_w, dinv,
                                                              b1, g1, be1, rm1, rv1,
                                                              bufB, nullptr, nullptr, nullptr);
    k_gemm<unsigned short><<<dim3(gbl), dim3(256), 0, stream>>>(bufB, DPAD, W2, bufA, N_NODES);
    k_agg<true><<<dim3(N_NODES / 4), dim3(256), 0, stream>>>(bufA, offs, csr_src, csr_w, dinv,
                                                             b2, g2, be2, rm2, rv2,
                                                             nullptr, bat, inv_cnt, outp);
}

// Round 3
// 681.528 us; speedup vs baseline: 1.1314x; 1.0506x over previous
//
#include <hip/hip_runtime.h>

#define N_NODES  50000
#define N_EDGES  1600000
#define N_GRAPHS 2048
#define DIM      133
#define DPAD     136          // bf16 elements per row (272 B, 16B-aligned rows)
#define EPSV     1e-5f

// ---- bf16 helpers (raw ushort; bf16 = top 16 bits of fp32) ----
__device__ __forceinline__ float blo(unsigned u) { return __uint_as_float(u << 16); }
__device__ __forceinline__ float bhi(unsigned u) { return __uint_as_float(u & 0xFFFF0000u); }
__device__ __forceinline__ unsigned short f2bf(float x) {
    unsigned v = __float_as_uint(x);
    return (unsigned short)((v + 0x7FFFu + ((v >> 16) & 1u)) >> 16);  // RNE
}
__device__ __forceinline__ unsigned packbf(float a, float b) {
    return (unsigned)f2bf(a) | ((unsigned)f2bf(b) << 16);
}

// ---------------- setup kernels ----------------

__global__ __launch_bounds__(256) void k_count(const int* __restrict__ col,
                                               const int* __restrict__ batch,
                                               int* __restrict__ deg,
                                               int* __restrict__ cnt)
{
    int idx = blockIdx.x * 256 + threadIdx.x;
    if (idx < N_EDGES) atomicAdd(&deg[col[idx]], 1);
    if (idx < N_NODES) atomicAdd(&cnt[batch[idx]], 1);
}

__global__ __launch_bounds__(256) void k_finalize(const int* __restrict__ deg,
                                                  const int* __restrict__ cnt,
                                                  float* __restrict__ dinv,
                                                  float* __restrict__ inv_cnt)
{
    int idx = blockIdx.x * 256 + threadIdx.x;
    if (idx < N_NODES)  dinv[idx]    = rsqrtf((float)deg[idx] + 1.0f); // +1 self loop
    if (idx < N_GRAPHS) inv_cnt[idx] = 1.0f / (float)max(cnt[idx], 1);
}

__global__ __launch_bounds__(256) void k_scan1(const int* __restrict__ deg,
                                               int* __restrict__ offs,
                                               int* __restrict__ bsum)
{
    __shared__ int sd[256];
    int t = threadIdx.x;
    int idx = blockIdx.x * 256 + t;
    int v = (idx < N_NODES) ? deg[idx] : 0;
    sd[t] = v; __syncthreads();
    for (int o = 1; o < 256; o <<= 1) {
        int add = (t >= o) ? sd[t - o] : 0;
        __syncthreads();
        sd[t] += add;
        __syncthreads();
    }
    if (idx < N_NODES) offs[idx] = sd[t] - v;
    if (t == 255) bsum[blockIdx.x] = sd[255];
}

__global__ __launch_bounds__(256) void k_scan2(const int* __restrict__ bsum,
                                               int* __restrict__ boff, int nb)
{
    __shared__ int sd[256];
    int t = threadIdx.x;
    int v = (t < nb) ? bsum[t] : 0;
    sd[t] = v; __syncthreads();
    for (int o = 1; o < 256; o <<= 1) {
        int add = (t >= o) ? sd[t - o] : 0;
        __syncthreads();
        sd[t] += add;
        __syncthreads();
    }
    boff[t] = sd[t] - v;
}

__global__ __launch_bounds__(256) void k_scan3(int* __restrict__ offs,
                                               const int* __restrict__ boff)
{
    int idx = blockIdx.x * 256 + threadIdx.x;
    if (idx < N_NODES)       offs[idx] += boff[blockIdx.x];
    else if (idx == N_NODES) offs[N_NODES] = N_EDGES;
}

// 2-byte CSR record: src node id (fits: 50000 < 65536). dinv looked up in k_agg.
__global__ __launch_bounds__(256) void k_fill(const int* __restrict__ row,
                                              const int* __restrict__ col,
                                              const int* __restrict__ offs,
                                              int* __restrict__ cursor,
                                              unsigned short* __restrict__ csr_src)
{
    int e = blockIdx.x * 256 + threadIdx.x;
    if (e < N_EDGES) {
        int c = col[e];
        int p = offs[c] + atomicAdd(&cursor[c], 1);
        csr_src[p] = (unsigned short)row[e];
    }
}

// ---------------- dense GEMM: H[M][DPAD](bf16) = A[M][lda] @ W[133][133] ----------------
// fp32 accumulation; A is fp32 (layer 1) or bf16 (layer 2); output stored bf16.

template <typename TIN>
__global__ __launch_bounds__(256, 2) void k_gemm(const TIN* __restrict__ A, int lda,
                                                 const float* __restrict__ W,
                                                 unsigned short* __restrict__ H, int M)
{
    __shared__ float xs[64][137];
    __shared__ float wsh[48][144];
    int t = threadIdx.x;
    int rowBase = blockIdx.x * 64;

    for (int idx = t; idx < 64 * DIM; idx += 256) {
        int r = idx / DIM, c = idx - r * DIM;
        int gr = rowBase + r;
        float v = 0.f;
        if (gr < M) {
            TIN raw = A[(size_t)gr * lda + c];
            if constexpr (sizeof(TIN) == 2) v = __uint_as_float((unsigned)raw << 16);
            else                            v = (float)raw;
        }
        xs[r][c] = v;
    }

    int r = t >> 2, cq = t & 3, c0 = cq * 36;
    float4 acc[9];
#pragma unroll
    for (int j = 0; j < 9; j++) acc[j] = make_float4(0.f, 0.f, 0.f, 0.f);

    for (int k0 = 0; k0 < DIM; k0 += 48) {
        int KC = min(48, DIM - k0);
        __syncthreads();
        for (int idx = t; idx < KC * DIM; idx += 256) {
            int kk = idx / DIM, c = idx - kk * DIM;
            wsh[kk][c] = W[(size_t)(k0 + kk) * DIM + c];
        }
        __syncthreads();
        for (int kk = 0; kk < KC; kk++) {
            float xv = xs[r][k0 + kk];
            const float4* wrow = (const float4*)&wsh[kk][c0];
#pragma unroll
            for (int j = 0; j < 9; j++) {
                float4 wv = wrow[j];
                acc[j].x += xv * wv.x; acc[j].y += xv * wv.y;
                acc[j].z += xv * wv.z; acc[j].w += xv * wv.w;
            }
        }
    }

    int gr = rowBase + r;
    if (gr < M) {
        unsigned short* Hr = H + (size_t)gr * DPAD;
#pragma unroll
        for (int j = 0; j < 9; j++) {
            int c = c0 + 4 * j;
            if (c >= DPAD) break;
            float v0 = (c + 0 < DIM) ? acc[j].x : 0.f;
            float v1 = (c + 1 < DIM) ? acc[j].y : 0.f;
            float v2 = (c + 2 < DIM) ? acc[j].z : 0.f;
            float v3 = (c + 3 < DIM) ? acc[j].w : 0.f;
            uint2 u;
            u.x = packbf(v0, v1);
            u.y = packbf(v2, v3);
            *(uint2*)(Hr + c) = u;   // 8B-aligned
        }
    }
}

// ---------------- fused aggregate + bias + ReLU + BN (+ optional mean-pool) ----------------
// out[i] = BN(relu(dinv[i]*(sum_e dinv[src]*h[src] + dinv[i]*h[i]) + b))

template <bool FINAL>
__global__ __launch_bounds__(256) void k_agg(const unsigned short* __restrict__ h,
                                             const int* __restrict__ offs,
                                             const unsigned short* __restrict__ csr_src,
                                             const float* __restrict__ dinv,
                                             const float* __restrict__ bias,
                                             const float* __restrict__ gam,
                                             const float* __restrict__ bet,
                                             const float* __restrict__ rmean,
                                             const float* __restrict__ rvar,
                                             unsigned short* __restrict__ y,
                                             const int* __restrict__ batch,
                                             const float* __restrict__ inv_cnt,
                                             float* __restrict__ outp)
{
    int node = blockIdx.x * 4 + (threadIdx.x >> 6);
    if (node >= N_NODES) return;
    int lane = threadIdx.x & 63;
    int l2 = lane & 3;

    float di = dinv[node];
    const unsigned* hrow = (const unsigned*)(h + (size_t)node * DPAD);
    unsigned p0 = hrow[lane];        // cols 2*lane, 2*lane+1
    unsigned p1 = hrow[64 + l2];     // cols 128+2*l2 (dup for lanes>=4, discarded)
    float2 a0; a0.x = di * blo(p0); a0.y = di * bhi(p0);   // self-loop term
    float2 a1; a1.x = di * blo(p1); a1.y = di * bhi(p1);

    int s0 = offs[node], s1 = offs[node + 1];
    for (int k0 = s0; k0 < s1; k0 += 64) {
        int nk = min(64, s1 - k0);
        int src = 0; float w = 0.f;
        if (lane < nk) {
            src = csr_src[k0 + lane];
            w   = dinv[src];          // L2-resident 200 KB table
        }
        for (int j = 0; j < nk; j++) {
            int   s  = __shfl(src, j);
            float ww = __shfl(w, j);
            const unsigned* hr = (const unsigned*)(h + (size_t)s * DPAD);
            unsigned q0 = hr[lane];
            unsigned q1 = hr[64 + l2];
            a0.x += ww * blo(q0); a0.y += ww * bhi(q0);
            a1.x += ww * blo(q1); a1.y += ww * bhi(q1);
        }
    }

    float ic = 0.f; int bg = 0;
    if (FINAL) { bg = batch[node]; ic = inv_cnt[bg]; }

    // main pair: cols 2*lane, 2*lane+1 (both < 128 < DIM)
    {
        int c = 2 * lane;
        float va = di * a0.x + bias[c];
        va = fmaxf(va, 0.f);
        va = (va - rmean[c]) * (gam[c] * rsqrtf(rvar[c] + EPSV)) + bet[c];
        int c1 = c + 1;
        float vb = di * a0.y + bias[c1];
        vb = fmaxf(vb, 0.f);
        vb = (vb - rmean[c1]) * (gam[c1] * rsqrtf(rvar[c1] + EPSV)) + bet[c1];
        if (FINAL) {
            atomicAdd(&outp[(size_t)bg * DIM + c],  va * ic);
            atomicAdd(&outp[(size_t)bg * DIM + c1], vb * ic);
        } else {
            ((unsigned*)((unsigned short*)y + (size_t)node * DPAD))[lane] = packbf(va, vb);
        }
    }
    // tail pair: cols 128+2*l2, 129+2*l2 (lanes 0..3 only)
    if (lane < 4) {
        int c = 128 + 2 * l2;
        float va = 0.f, vb = 0.f;
        if (c < DIM) {
            va = di * a1.x + bias[c];
            va = fmaxf(va, 0.f);
            va = (va - rmean[c]) * (gam[c] * rsqrtf(rvar[c] + EPSV)) + bet[c];
        }
        int c1 = c + 1;
        if (c1 < DIM) {
            vb = di * a1.y + bias[c1];
            vb = fmaxf(vb, 0.f);
            vb = (vb - rmean[c1]) * (gam[c1] * rsqrtf(rvar[c1] + EPSV)) + bet[c1];
        }
        if (FINAL) {
            if (c  < DIM) atomicAdd(&outp[(size_t)bg * DIM + c],  va * ic);
            if (c1 < DIM) atomicAdd(&outp[(size_t)bg * DIM + c1], vb * ic);
        } else {
            ((unsigned*)((unsigned short*)y + (size_t)node * DPAD))[64 + l2] = packbf(va, vb);
        }
    }
}

// ---------------- launch ----------------

extern "C" void kernel_launch(void* const* d_in, const int* in_sizes, int n_in,
                              void* d_out, int out_size, void* d_ws, size_t ws_size,
                              hipStream_t stream)
{
    const float* x   = (const float*)d_in[0];
    const int*   ei  = (const int*)d_in[1];
    const int*   bat = (const int*)d_in[2];
    const float* W1  = (const float*)d_in[3];
    const float* b1  = (const float*)d_in[4];
    const float* W2  = (const float*)d_in[5];
    const float* b2  = (const float*)d_in[6];
    const float* g1  = (const float*)d_in[7];
    const float* be1 = (const float*)d_in[8];
    const float* rm1 = (const float*)d_in[9];
    const float* rv1 = (const float*)d_in[10];
    const float* g2  = (const float*)d_in[11];
    const float* be2 = (const float*)d_in[12];
    const float* rm2 = (const float*)d_in[13];
    const float* rv2 = (const float*)d_in[14];
    float* outp = (float*)d_out;
    char* ws = (char*)d_ws;

    int*   deg     = (int*)  (ws + 0);         // 200000 B
    int*   cursor  = (int*)  (ws + 200000);    // 200000 B
    int*   cnt     = (int*)  (ws + 400000);    //   8192 B
    int*   offs    = (int*)  (ws + 408192);    // 200016 B (N+1 ints)
    float* dinv    = (float*)(ws + 608208);    // 200000 B
    float* inv_cnt = (float*)(ws + 808208);    //   8192 B
    int*   bsum    = (int*)  (ws + 816400);    //   1024 B
    int*   boff    = (int*)  (ws + 817424);    //   1024 B
    unsigned short* csr_src = (unsigned short*)(ws + 818448); // 3.2 MB (1.6M x u16)
    unsigned short* bufA = (unsigned short*)(ws + 4018448);   // 13.6 MB (50000 x 136 bf16)
    unsigned short* bufB = (unsigned short*)(ws + 17618448);  // 13.6 MB

    hipMemsetAsync(ws, 0, 408192, stream);                       // deg, cursor, cnt
    hipMemsetAsync(d_out, 0, (size_t)out_size * 4, stream);

    const int* row = ei;
    const int* col = ei + N_EDGES;

    int ebl = (N_EDGES + 255) / 256;
    int nbl = (N_NODES + 255) / 256;

    k_count   <<<dim3(ebl), dim3(256), 0, stream>>>(col, bat, deg, cnt);
    k_finalize<<<dim3(nbl), dim3(256), 0, stream>>>(deg, cnt, dinv, inv_cnt);
    k_scan1   <<<dim3(nbl), dim3(256), 0, stream>>>(deg, offs, bsum);
    k_scan2   <<<dim3(1),   dim3(256), 0, stream>>>(bsum, boff, nbl);
    k_scan3   <<<dim3(nbl), dim3(256), 0, stream>>>(offs, boff);
    k_fill    <<<dim3(ebl), dim3(256), 0, stream>>>(row, col, offs, cursor, csr_src);

    int gbl = (N_NODES + 63) / 64;
    k_gemm<float><<<dim3(gbl), dim3(256), 0, stream>>>(x, DIM, W1, bufA, N_NODES);
    k_agg<false><<<dim3(N_NODES / 4), dim3(256), 0, stream>>>(bufA, offs, csr_src, dinv,
                                                              b1, g1, be1, rm1, rv1,
                                                              bufB, nullptr, nullptr, nullptr);
    k_gemm<unsigned short><<<dim3(gbl), dim3(256), 0, stream>>>(bufB, DPAD, W2, bufA, N_NODES);
    k_agg<true><<<dim3(N_NODES / 4), dim3(256), 0, stream>>>(bufA, offs, csr_src, dinv,
                                                             b2, g2, be2, rm2, rv2,
                                                             nullptr, bat, inv_cnt, outp);
}

// Round 4
// 596.506 us; speedup vs baseline: 1.2926x; 1.1425x over previous
//
#include <hip/hip_runtime.h>

#define N_NODES  50000
#define N_EDGES  1600000
#define N_GRAPHS 2048
#define DIM      133
#define DPAD     136          // bf16 elements per row (272 B, 16B-aligned rows)
#define EPSV     1e-5f

// ---- bf16 helpers (raw ushort; bf16 = top 16 bits of fp32) ----
__device__ __forceinline__ float blo(unsigned u) { return __uint_as_float(u << 16); }
__device__ __forceinline__ float bhi(unsigned u) { return __uint_as_float(u & 0xFFFF0000u); }
__device__ __forceinline__ unsigned short f2bf(float x) {
    unsigned v = __float_as_uint(x);
    return (unsigned short)((v + 0x7FFFu + ((v >> 16) & 1u)) >> 16);  // RNE
}
__device__ __forceinline__ unsigned packbf(float a, float b) {
    return (unsigned)f2bf(a) | ((unsigned)f2bf(b) << 16);
}

// ---------------- setup kernels ----------------

__global__ __launch_bounds__(256) void k_count(const int* __restrict__ col,
                                               const int* __restrict__ batch,
                                               int* __restrict__ deg,
                                               int* __restrict__ cnt)
{
    int idx = blockIdx.x * 256 + threadIdx.x;
    if (idx < N_EDGES) atomicAdd(&deg[col[idx]], 1);
    if (idx < N_NODES) atomicAdd(&cnt[batch[idx]], 1);
}

__global__ __launch_bounds__(256) void k_finalize(const int* __restrict__ deg,
                                                  const int* __restrict__ cnt,
                                                  float* __restrict__ dinv,
                                                  float* __restrict__ inv_cnt)
{
    int idx = blockIdx.x * 256 + threadIdx.x;
    if (idx < N_NODES)  dinv[idx]    = rsqrtf((float)deg[idx] + 1.0f); // +1 self loop
    if (idx < N_GRAPHS) inv_cnt[idx] = 1.0f / (float)max(cnt[idx], 1);
}

__global__ __launch_bounds__(256) void k_scan1(const int* __restrict__ deg,
                                               int* __restrict__ offs,
                                               int* __restrict__ bsum)
{
    __shared__ int sd[256];
    int t = threadIdx.x;
    int idx = blockIdx.x * 256 + t;
    int v = (idx < N_NODES) ? deg[idx] : 0;
    sd[t] = v; __syncthreads();
    for (int o = 1; o < 256; o <<= 1) {
        int add = (t >= o) ? sd[t - o] : 0;
        __syncthreads();
        sd[t] += add;
        __syncthreads();
    }
    if (idx < N_NODES) offs[idx] = sd[t] - v;
    if (t == 255) bsum[blockIdx.x] = sd[255];
}

__global__ __launch_bounds__(256) void k_scan2(const int* __restrict__ bsum,
                                               int* __restrict__ boff, int nb)
{
    __shared__ int sd[256];
    int t = threadIdx.x;
    int v = (t < nb) ? bsum[t] : 0;
    sd[t] = v; __syncthreads();
    for (int o = 1; o < 256; o <<= 1) {
        int add = (t >= o) ? sd[t - o] : 0;
        __syncthreads();
        sd[t] += add;
        __syncthreads();
    }
    boff[t] = sd[t] - v;
}

__global__ __launch_bounds__(256) void k_scan3(int* __restrict__ offs,
                                               const int* __restrict__ boff)
{
    int idx = blockIdx.x * 256 + threadIdx.x;
    if (idx < N_NODES)       offs[idx] += boff[blockIdx.x];
    else if (idx == N_NODES) offs[N_NODES] = N_EDGES;
}

// 2-byte CSR record: src node id (fits: 50000 < 65536). dinv looked up in k_agg.
__global__ __launch_bounds__(256) void k_fill(const int* __restrict__ row,
                                              const int* __restrict__ col,
                                              const int* __restrict__ offs,
                                              int* __restrict__ cursor,
                                              unsigned short* __restrict__ csr_src)
{
    int e = blockIdx.x * 256 + threadIdx.x;
    if (e < N_EDGES) {
        int c = col[e];
        int p = offs[c] + atomicAdd(&cursor[c], 1);
        csr_src[p] = (unsigned short)row[e];
    }
}

// ---------------- dense GEMM: H[M][DPAD](bf16) = A[M][lda] @ W[133][133] ----------------
// fp32 accumulation; A is fp32 (layer 1) or bf16 (layer 2); output stored bf16.

template <typename TIN>
__global__ __launch_bounds__(256, 2) void k_gemm(const TIN* __restrict__ A, int lda,
                                                 const float* __restrict__ W,
                                                 unsigned short* __restrict__ H, int M)
{
    __shared__ float xs[64][137];
    __shared__ float wsh[48][144];
    int t = threadIdx.x;
    int rowBase = blockIdx.x * 64;

    for (int idx = t; idx < 64 * DIM; idx += 256) {
        int r = idx / DIM, c = idx - r * DIM;
        int gr = rowBase + r;
        float v = 0.f;
        if (gr < M) {
            TIN raw = A[(size_t)gr * lda + c];
            if constexpr (sizeof(TIN) == 2) v = __uint_as_float((unsigned)raw << 16);
            else                            v = (float)raw;
        }
        xs[r][c] = v;
    }

    int r = t >> 2, cq = t & 3, c0 = cq * 36;
    float4 acc[9];
#pragma unroll
    for (int j = 0; j < 9; j++) acc[j] = make_float4(0.f, 0.f, 0.f, 0.f);

    for (int k0 = 0; k0 < DIM; k0 += 48) {
        int KC = min(48, DIM - k0);
        __syncthreads();
        for (int idx = t; idx < KC * DIM; idx += 256) {
            int kk = idx / DIM, c = idx - kk * DIM;
            wsh[kk][c] = W[(size_t)(k0 + kk) * DIM + c];
        }
        __syncthreads();
        for (int kk = 0; kk < KC; kk++) {
            float xv = xs[r][k0 + kk];
            const float4* wrow = (const float4*)&wsh[kk][c0];
#pragma unroll
            for (int j = 0; j < 9; j++) {
                float4 wv = wrow[j];
                acc[j].x += xv * wv.x; acc[j].y += xv * wv.y;
                acc[j].z += xv * wv.z; acc[j].w += xv * wv.w;
            }
        }
    }

    int gr = rowBase + r;
    if (gr < M) {
        unsigned short* Hr = H + (size_t)gr * DPAD;
#pragma unroll
        for (int j = 0; j < 9; j++) {
            int c = c0 + 4 * j;
            if (c >= DPAD) break;
            float v0 = (c + 0 < DIM) ? acc[j].x : 0.f;
            float v1 = (c + 1 < DIM) ? acc[j].y : 0.f;
            float v2 = (c + 2 < DIM) ? acc[j].z : 0.f;
            float v3 = (c + 3 < DIM) ? acc[j].w : 0.f;
            uint2 u;
            u.x = packbf(v0, v1);
            u.y = packbf(v2, v3);
            *(uint2*)(Hr + c) = u;   // 8B-aligned
        }
    }
}

// ---------------- fused aggregate + bias + ReLU + BN (+ optional mean-pool) ----------------
// out[i] = BN(relu(dinv[i]*(sum_e dinv[src]*h[src] + dinv[i]*h[i]) + b))
// 4x-unrolled gather loop: 8 independent loads in flight; SGPR base addressing
// via readfirstlane (post-shfl values are wave-uniform; all 64 lanes active).

template <bool FINAL>
__global__ __launch_bounds__(256) void k_agg(const unsigned short* __restrict__ h,
                                             const int* __restrict__ offs,
                                             const unsigned short* __restrict__ csr_src,
                                             const float* __restrict__ dinv,
                                             const float* __restrict__ bias,
                                             const float* __restrict__ gam,
                                             const float* __restrict__ bet,
                                             const float* __restrict__ rmean,
                                             const float* __restrict__ rvar,
                                             unsigned short* __restrict__ y,
                                             const int* __restrict__ batch,
                                             const float* __restrict__ inv_cnt,
                                             float* __restrict__ outp)
{
    int node = blockIdx.x * 4 + (threadIdx.x >> 6);
    if (node >= N_NODES) return;
    int lane = threadIdx.x & 63;
    int l2 = lane & 3;

    float di = dinv[node];
    const unsigned* hrow = (const unsigned*)(h + (size_t)node * DPAD);
    unsigned p0 = hrow[lane];        // cols 2*lane, 2*lane+1
    unsigned p1 = hrow[64 + l2];     // cols 128+2*l2 (dup for lanes>=4, discarded)
    float2 a0; a0.x = di * blo(p0); a0.y = di * bhi(p0);   // self-loop term
    float2 a1; a1.x = di * blo(p1); a1.y = di * bhi(p1);

    int s0 = offs[node], s1 = offs[node + 1];
    for (int k0 = s0; k0 < s1; k0 += 64) {
        int nk = min(64, s1 - k0);
        int src = 0; float w = 0.f;
        if (lane < nk) {
            src = csr_src[k0 + lane];
            w   = dinv[src];          // L2-resident 200 KB table
        }
        int j = 0;
        for (; j + 4 <= nk; j += 4) {
            int sA = __builtin_amdgcn_readfirstlane(__shfl(src, j + 0));
            int sB = __builtin_amdgcn_readfirstlane(__shfl(src, j + 1));
            int sC = __builtin_amdgcn_readfirstlane(__shfl(src, j + 2));
            int sD = __builtin_amdgcn_readfirstlane(__shfl(src, j + 3));
            float wA = __shfl(w, j + 0);
            float wB = __shfl(w, j + 1);
            float wC = __shfl(w, j + 2);
            float wD = __shfl(w, j + 3);
            const unsigned* rA = (const unsigned*)(h + (size_t)sA * DPAD);
            const unsigned* rB = (const unsigned*)(h + (size_t)sB * DPAD);
            const unsigned* rC = (const unsigned*)(h + (size_t)sC * DPAD);
            const unsigned* rD = (const unsigned*)(h + (size_t)sD * DPAD);
            unsigned qA0 = rA[lane], qA1 = rA[64 + l2];
            unsigned qB0 = rB[lane], qB1 = rB[64 + l2];
            unsigned qC0 = rC[lane], qC1 = rC[64 + l2];
            unsigned qD0 = rD[lane], qD1 = rD[64 + l2];
            a0.x += wA * blo(qA0); a0.y += wA * bhi(qA0);
            a1.x += wA * blo(qA1); a1.y += wA * bhi(qA1);
            a0.x += wB * blo(qB0); a0.y += wB * bhi(qB0);
            a1.x += wB * blo(qB1); a1.y += wB * bhi(qB1);
            a0.x += wC * blo(qC0); a0.y += wC * bhi(qC0);
            a1.x += wC * blo(qC1); a1.y += wC * bhi(qC1);
            a0.x += wD * blo(qD0); a0.y += wD * bhi(qD0);
            a1.x += wD * blo(qD1); a1.y += wD * bhi(qD1);
        }
        for (; j < nk; j++) {
            int   s  = __builtin_amdgcn_readfirstlane(__shfl(src, j));
            float ww = __shfl(w, j);
            const unsigned* hr = (const unsigned*)(h + (size_t)s * DPAD);
            unsigned q0 = hr[lane];
            unsigned q1 = hr[64 + l2];
            a0.x += ww * blo(q0); a0.y += ww * bhi(q0);
            a1.x += ww * blo(q1); a1.y += ww * bhi(q1);
        }
    }

    float ic = 0.f; int bg = 0;
    if (FINAL) { bg = batch[node]; ic = inv_cnt[bg]; }

    // main pair: cols 2*lane, 2*lane+1 (both < 128 < DIM)
    {
        int c = 2 * lane;
        float va = di * a0.x + bias[c];
        va = fmaxf(va, 0.f);
        va = (va - rmean[c]) * (gam[c] * rsqrtf(rvar[c] + EPSV)) + bet[c];
        int c1 = c + 1;
        float vb = di * a0.y + bias[c1];
        vb = fmaxf(vb, 0.f);
        vb = (vb - rmean[c1]) * (gam[c1] * rsqrtf(rvar[c1] + EPSV)) + bet[c1];
        if (FINAL) {
            atomicAdd(&outp[(size_t)bg * DIM + c],  va * ic);
            atomicAdd(&outp[(size_t)bg * DIM + c1], vb * ic);
        } else {
            ((unsigned*)((unsigned short*)y + (size_t)node * DPAD))[lane] = packbf(va, vb);
        }
    }
    // tail pair: cols 128+2*l2, 129+2*l2 (lanes 0..3 only)
    if (lane < 4) {
        int c = 128 + 2 * l2;
        float va = 0.f, vb = 0.f;
        if (c < DIM) {
            va = di * a1.x + bias[c];
            va = fmaxf(va, 0.f);
            va = (va - rmean[c]) * (gam[c] * rsqrtf(rvar[c] + EPSV)) + bet[c];
        }
        int c1 = c + 1;
        if (c1 < DIM) {
            vb = di * a1.y + bias[c1];
            vb = fmaxf(vb, 0.f);
            vb = (vb - rmean[c1]) * (gam[c1] * rsqrtf(rvar[c1] + EPSV)) + bet[c1];
        }
        if (FINAL) {
            if (c  < DIM) atomicAdd(&outp[(size_t)bg * DIM + c],  va * ic);
            if (c1 < DIM) atomicAdd(&outp[(size_t)bg * DIM + c1], vb * ic);
        } else {
            ((unsigned*)((unsigned short*)y + (size_t)node * DPAD))[64 + l2] = packbf(va, vb);
        }
    }
}

// ---------------- launch ----------------

extern "C" void kernel_launch(void* const* d_in, const int* in_sizes, int n_in,
                              void* d_out, int out_size, void* d_ws, size_t ws_size,
                              hipStream_t stream)
{
    const float* x   = (const float*)d_in[0];
    const int*   ei  = (const int*)d_in[1];
    const int*   bat = (const int*)d_in[2];
    const float* W1  = (const float*)d_in[3];
    const float* b1  = (const float*)d_in[4];
    const float* W2  = (const float*)d_in[5];
    const float* b2  = (const float*)d_in[6];
    const float* g1  = (const float*)d_in[7];
    const float* be1 = (const float*)d_in[8];
    const float* rm1 = (const float*)d_in[9];
    const float* rv1 = (const float*)d_in[10];
    const float* g2  = (const float*)d_in[11];
    const float* be2 = (const float*)d_in[12];
    const float* rm2 = (const float*)d_in[13];
    const float* rv2 = (const float*)d_in[14];
    float* outp = (float*)d_out;
    char* ws = (char*)d_ws;

    int*   deg     = (int*)  (ws + 0);         // 200000 B
    int*   cursor  = (int*)  (ws + 200000);    // 200000 B
    int*   cnt     = (int*)  (ws + 400000);    //   8192 B
    int*   offs    = (int*)  (ws + 408192);    // 200016 B (N+1 ints)
    float* dinv    = (float*)(ws + 608208);    // 200000 B
    float* inv_cnt = (float*)(ws + 808208);    //   8192 B
    int*   bsum    = (int*)  (ws + 816400);    //   1024 B
    int*   boff    = (int*)  (ws + 817424);    //   1024 B
    unsigned short* csr_src = (unsigned short*)(ws + 818448); // 3.2 MB (1.6M x u16)
    unsigned short* bufA = (unsigned short*)(ws + 4018448);   // 13.6 MB (50000 x 136 bf16)
    unsigned short* bufB = (unsigned short*)(ws + 17618448);  // 13.6 MB

    hipMemsetAsync(ws, 0, 408192, stream);                       // deg, cursor, cnt
    hipMemsetAsync(d_out, 0, (size_t)out_size * 4, stream);

    const int* row = ei;
    const int* col = ei + N_EDGES;

    int ebl = (N_EDGES + 255) / 256;
    int nbl = (N_NODES + 255) / 256;

    k_count   <<<dim3(ebl), dim3(256), 0, stream>>>(col, bat, deg, cnt);
    k_finalize<<<dim3(nbl), dim3(256), 0, stream>>>(deg, cnt, dinv, inv_cnt);
    k_scan1   <<<dim3(nbl), dim3(256), 0, stream>>>(deg, offs, bsum);
    k_scan2   <<<dim3(1),   dim3(256), 0, stream>>>(bsum, boff, nbl);
    k_scan3   <<<dim3(nbl), dim3(256), 0, stream>>>(offs, boff);
    k_fill    <<<dim3(ebl), dim3(256), 0, stream>>>(row, col, offs, cursor, csr_src);

    int gbl = (N_NODES + 63) / 64;
    k_gemm<float><<<dim3(gbl), dim3(256), 0, stream>>>(x, DIM, W1, bufA, N_NODES);
    k_agg<false><<<dim3(N_NODES / 4), dim3(256), 0, stream>>>(bufA, offs, csr_src, dinv,
                                                              b1, g1, be1, rm1, rv1,
                                                              bufB, nullptr, nullptr, nullptr);
    k_gemm<unsigned short><<<dim3(gbl), dim3(256), 0, stream>>>(bufB, DPAD, W2, bufA, N_NODES);
    k_agg<true><<<dim3(N_NODES / 4), dim3(256), 0, stream>>>(bufA, offs, csr_src, dinv,
                                                             b2, g2, be2, rm2, rv2,
                                                             nullptr, bat, inv_cnt, outp);
}

// Round 5
// 484.622 us; speedup vs baseline: 1.5911x; 1.2309x over previous
//
#include <hip/hip_runtime.h>

#define N_NODES  50000
#define N_ROWS   50048        // padded row count (multiple of 64)
#define N_EDGES  1600000
#define N_GRAPHS 2048
#define DIM      133
#define HSTR     136          // bf16 row stride for gemm-output / agg-input buffers
#define YSTR     160          // bf16 row stride for gemm-input buffers (K padded to 160)
#define EPSV     1e-5f

typedef __attribute__((ext_vector_type(8))) short bf16x8;
typedef __attribute__((ext_vector_type(4))) float f32x4;

// ---- bf16 helpers (raw ushort; bf16 = top 16 bits of fp32) ----
__device__ __forceinline__ float blo(unsigned u) { return __uint_as_float(u << 16); }
__device__ __forceinline__ float bhi(unsigned u) { return __uint_as_float(u & 0xFFFF0000u); }
__device__ __forceinline__ unsigned short f2bf(float x) {
    unsigned v = __float_as_uint(x);
    return (unsigned short)((v + 0x7FFFu + ((v >> 16) & 1u)) >> 16);  // RNE
}
__device__ __forceinline__ unsigned packbf(float a, float b) {
    return (unsigned)f2bf(a) | ((unsigned)f2bf(b) << 16);
}

// ---------------- setup kernels ----------------

__global__ __launch_bounds__(256) void k_count(const int* __restrict__ col,
                                               const int* __restrict__ batch,
                                               int* __restrict__ deg,
                                               int* __restrict__ cnt)
{
    int idx = blockIdx.x * 256 + threadIdx.x;
    if (idx < N_EDGES) atomicAdd(&deg[col[idx]], 1);
    if (idx < N_NODES) atomicAdd(&cnt[batch[idx]], 1);
}

__global__ __launch_bounds__(256) void k_finalize(const int* __restrict__ deg,
                                                  const int* __restrict__ cnt,
                                                  float* __restrict__ dinv,
                                                  float* __restrict__ inv_cnt)
{
    int idx = blockIdx.x * 256 + threadIdx.x;
    if (idx < N_NODES)  dinv[idx]    = rsqrtf((float)deg[idx] + 1.0f); // +1 self loop
    if (idx < N_GRAPHS) inv_cnt[idx] = 1.0f / (float)max(cnt[idx], 1);
}

__global__ __launch_bounds__(256) void k_scan1(const int* __restrict__ deg,
                                               int* __restrict__ offs,
                                               int* __restrict__ bsum)
{
    __shared__ int sd[256];
    int t = threadIdx.x;
    int idx = blockIdx.x * 256 + t;
    int v = (idx < N_NODES) ? deg[idx] : 0;
    sd[t] = v; __syncthreads();
    for (int o = 1; o < 256; o <<= 1) {
        int add = (t >= o) ? sd[t - o] : 0;
        __syncthreads();
        sd[t] += add;
        __syncthreads();
    }
    if (idx < N_NODES) offs[idx] = sd[t] - v;
    if (t == 255) bsum[blockIdx.x] = sd[255];
}

__global__ __launch_bounds__(256) void k_scan2(const int* __restrict__ bsum,
                                               int* __restrict__ boff, int nb)
{
    __shared__ int sd[256];
    int t = threadIdx.x;
    int v = (t < nb) ? bsum[t] : 0;
    sd[t] = v; __syncthreads();
    for (int o = 1; o < 256; o <<= 1) {
        int add = (t >= o) ? sd[t - o] : 0;
        __syncthreads();
        sd[t] += add;
        __syncthreads();
    }
    boff[t] = sd[t] - v;
}

__global__ __launch_bounds__(256) void k_scan3(int* __restrict__ offs,
                                               const int* __restrict__ boff)
{
    int idx = blockIdx.x * 256 + threadIdx.x;
    if (idx < N_NODES)       offs[idx] += boff[blockIdx.x];
    else if (idx == N_NODES) offs[N_NODES] = N_EDGES;
}

// 2-byte CSR record: src node id (fits: 50000 < 65536). dinv looked up in k_agg.
__global__ __launch_bounds__(256) void k_fill(const int* __restrict__ row,
                                              const int* __restrict__ col,
                                              const int* __restrict__ offs,
                                              int* __restrict__ cursor,
                                              unsigned short* __restrict__ csr_src)
{
    int e = blockIdx.x * 256 + threadIdx.x;
    if (e < N_EDGES) {
        int c = col[e];
        int p = offs[c] + atomicAdd(&cursor[c], 1);
        csr_src[p] = (unsigned short)row[e];
    }
}

// ---- pack W (fp32 [133][133], W[k][n]) into MFMA B-fragment layout ----
// Wbf[((t*5 + kc)*64 + lane)*8 + j] = bf16(W[kc*32 + (lane>>4)*8 + j][t*16 + (lane&15)])
__global__ __launch_bounds__(256) void k_w2bf(const float* __restrict__ W,
                                              unsigned short* __restrict__ Wbf)
{
    int idx = blockIdx.x * 256 + threadIdx.x;          // 9*5*64*8 = 23040
    if (idx >= 23040) return;
    int j    = idx & 7;
    int lane = (idx >> 3) & 63;
    int kc   = (idx >> 9) % 5;
    int t    = idx / (8 * 64 * 5);
    int k = kc * 32 + (lane >> 4) * 8 + j;
    int n = t * 16 + (lane & 15);
    float v = (k < DIM && n < DIM) ? W[k * DIM + n] : 0.f;
    Wbf[idx] = f2bf(v);
}

// ---- convert x fp32 [N][133] -> bf16 [N][160] with zero K-padding ----
__global__ __launch_bounds__(256) void k_x2bf(const float* __restrict__ x,
                                              unsigned* __restrict__ Abf) // uint = 2 bf16
{
    int idx = blockIdx.x * 256 + threadIdx.x;          // N_NODES * 80
    if (idx >= N_NODES * 80) return;
    int r  = idx / 80;
    int c2 = (idx - r * 80) * 2;
    float a = (c2     < DIM) ? x[(size_t)r * DIM + c2]     : 0.f;
    float b = (c2 + 1 < DIM) ? x[(size_t)r * DIM + c2 + 1] : 0.f;
    Abf[idx] = packbf(a, b);
}

// ---------------- MFMA GEMM: H[M][HSTR](bf16) = A[.][YSTR](bf16) @ W ----------------
// 4 waves/block; wave w: rows [blk*64 + w*16, +16), 9 n-tiles of 16, K = 5 chunks of 32.
// A-frag: lane holds A[m=lane&15][k=quad*8+j]; B pre-packed; D: col=lane&15,row=quad*4+reg.
__global__ __launch_bounds__(256) void k_gemm_mfma(const unsigned short* __restrict__ A,
                                                   const unsigned short* __restrict__ Wbf,
                                                   unsigned short* __restrict__ H, int M)
{
    int wave = threadIdx.x >> 6, lane = threadIdx.x & 63;
    int quad = lane >> 4, l16 = lane & 15;
    int m = blockIdx.x * 64 + wave * 16 + l16;         // < N_ROWS always (allocated)

    const bf16x8* Arow = (const bf16x8*)(A + (size_t)m * YSTR);  // frag idx = kc*4 + quad
    const bf16x8* Bq   = (const bf16x8*)Wbf;                      // idx = (t*5+kc)*64 + lane

    f32x4 acc[9] = {};
#pragma unroll
    for (int kc = 0; kc < 5; kc++) {
        bf16x8 af = Arow[kc * 4 + quad];
#pragma unroll
        for (int t = 0; t < 9; t++) {
            bf16x8 bfr = Bq[(t * 5 + kc) * 64 + lane];
            acc[t] = __builtin_amdgcn_mfma_f32_16x16x32_bf16(af, bfr, acc[t], 0, 0, 0);
        }
    }

    int gr0 = blockIdx.x * 64 + wave * 16 + quad * 4;
#pragma unroll
    for (int t = 0; t < 9; t++) {
        int c = t * 16 + l16;
#pragma unroll
        for (int reg = 0; reg < 4; reg++) {
            int gr = gr0 + reg;
            if (gr < M && c < HSTR) {
                float v = (c < DIM) ? acc[t][reg] : 0.f;   // zero pad cols 133..135
                H[(size_t)gr * HSTR + c] = f2bf(v);
            }
        }
    }
}

// ---------------- fused aggregate + bias + ReLU + BN (+ optional mean-pool) ----------------
// out[i] = BN(relu(dinv[i]*(sum_e dinv[src]*h[src] + dinv[i]*h[i]) + b))
// h: bf16 stride HSTR. Non-final output y: bf16 stride YSTR, zero-padded cols 133..159.

template <bool FINAL>
__global__ __launch_bounds__(256) void k_agg(const unsigned short* __restrict__ h,
                                             const int* __restrict__ offs,
                                             const unsigned short* __restrict__ csr_src,
                                             const float* __restrict__ dinv,
                                             const float* __restrict__ bias,
                                             const float* __restrict__ gam,
                                             const float* __restrict__ bet,
                                             const float* __restrict__ rmean,
                                             const float* __restrict__ rvar,
                                             unsigned short* __restrict__ y,
                                             const int* __restrict__ batch,
                                             const float* __restrict__ inv_cnt,
                                             float* __restrict__ outp)
{
    int node = blockIdx.x * 4 + (threadIdx.x >> 6);
    if (node >= N_NODES) return;
    int lane = threadIdx.x & 63;
    int l2 = lane & 3;

    float di = dinv[node];
    const unsigned* hrow = (const unsigned*)(h + (size_t)node * HSTR);
    unsigned p0 = hrow[lane];        // cols 2*lane, 2*lane+1
    unsigned p1 = hrow[64 + l2];     // cols 128+2*l2 (dup for lanes>=4, discarded)
    float2 a0; a0.x = di * blo(p0); a0.y = di * bhi(p0);   // self-loop term
    float2 a1; a1.x = di * blo(p1); a1.y = di * bhi(p1);

    int s0 = offs[node], s1 = offs[node + 1];
    for (int k0 = s0; k0 < s1; k0 += 64) {
        int nk = min(64, s1 - k0);
        int src = 0; float w = 0.f;
        if (lane < nk) {
            src = csr_src[k0 + lane];
            w   = dinv[src];          // L2-resident 200 KB table
        }
        int j = 0;
        for (; j + 4 <= nk; j += 4) {
            int sA = __builtin_amdgcn_readfirstlane(__shfl(src, j + 0));
            int sB = __builtin_amdgcn_readfirstlane(__shfl(src, j + 1));
            int sC = __builtin_amdgcn_readfirstlane(__shfl(src, j + 2));
            int sD = __builtin_amdgcn_readfirstlane(__shfl(src, j + 3));
            float wA = __shfl(w, j + 0);
            float wB = __shfl(w, j + 1);
            float wC = __shfl(w, j + 2);
            float wD = __shfl(w, j + 3);
            const unsigned* rA = (const unsigned*)(h + (size_t)sA * HSTR);
            const unsigned* rB = (const unsigned*)(h + (size_t)sB * HSTR);
            const unsigned* rC = (const unsigned*)(h + (size_t)sC * HSTR);
            const unsigned* rD = (const unsigned*)(h + (size_t)sD * HSTR);
            unsigned qA0 = rA[lane], qA1 = rA[64 + l2];
            unsigned qB0 = rB[lane], qB1 = rB[64 + l2];
            unsigned qC0 = rC[lane], qC1 = rC[64 + l2];
            unsigned qD0 = rD[lane], qD1 = rD[64 + l2];
            a0.x += wA * blo(qA0); a0.y += wA * bhi(qA0);
            a1.x += wA * blo(qA1); a1.y += wA * bhi(qA1);
            a0.x += wB * blo(qB0); a0.y += wB * bhi(qB0);
            a1.x += wB * blo(qB1); a1.y += wB * bhi(qB1);
            a0.x += wC * blo(qC0); a0.y += wC * bhi(qC0);
            a1.x += wC * blo(qC1); a1.y += wC * bhi(qC1);
            a0.x += wD * blo(qD0); a0.y += wD * bhi(qD0);
            a1.x += wD * blo(qD1); a1.y += wD * bhi(qD1);
        }
        for (; j < nk; j++) {
            int   s  = __builtin_amdgcn_readfirstlane(__shfl(src, j));
            float ww = __shfl(w, j);
            const unsigned* hr = (const unsigned*)(h + (size_t)s * HSTR);
            unsigned q0 = hr[lane];
            unsigned q1 = hr[64 + l2];
            a0.x += ww * blo(q0); a0.y += ww * bhi(q0);
            a1.x += ww * blo(q1); a1.y += ww * bhi(q1);
        }
    }

    float ic = 0.f; int bg = 0;
    if (FINAL) { bg = batch[node]; ic = inv_cnt[bg]; }

    // main pair: cols 2*lane, 2*lane+1 (both < 128 < DIM)
    {
        int c = 2 * lane;
        float va = di * a0.x + bias[c];
        va = fmaxf(va, 0.f);
        va = (va - rmean[c]) * (gam[c] * rsqrtf(rvar[c] + EPSV)) + bet[c];
        int c1 = c + 1;
        float vb = di * a0.y + bias[c1];
        vb = fmaxf(vb, 0.f);
        vb = (vb - rmean[c1]) * (gam[c1] * rsqrtf(rvar[c1] + EPSV)) + bet[c1];
        if (FINAL) {
            atomicAdd(&outp[(size_t)bg * DIM + c],  va * ic);
            atomicAdd(&outp[(size_t)bg * DIM + c1], vb * ic);
        } else {
            ((unsigned*)(y + (size_t)node * YSTR))[lane] = packbf(va, vb);
        }
    }
    // tail: cols 128..159. lanes 0-3 compute cols 128+2*l2 (masked >=133); lanes 4-15 pad zeros.
    if (lane < 16) {
        float va = 0.f, vb = 0.f;
        if (lane < 4) {
            int c = 128 + 2 * l2;
            if (c < DIM) {
                va = di * a1.x + bias[c];
                va = fmaxf(va, 0.f);
                va = (va - rmean[c]) * (gam[c] * rsqrtf(rvar[c] + EPSV)) + bet[c];
            }
            int c1 = c + 1;
            if (c1 < DIM) {
                vb = di * a1.y + bias[c1];
                vb = fmaxf(vb, 0.f);
                vb = (vb - rmean[c1]) * (gam[c1] * rsqrtf(rvar[c1] + EPSV)) + bet[c1];
            }
            if (FINAL) {
                if (c  < DIM) atomicAdd(&outp[(size_t)bg * DIM + c],  va * ic);
                if (c1 < DIM) atomicAdd(&outp[(size_t)bg * DIM + c1], vb * ic);
            }
        }
        if (!FINAL)
            ((unsigned*)(y + (size_t)node * YSTR))[64 + lane] = packbf(va, vb);
    }
}

// ---------------- launch ----------------

extern "C" void kernel_launch(void* const* d_in, const int* in_sizes, int n_in,
                              void* d_out, int out_size, void* d_ws, size_t ws_size,
                              hipStream_t stream)
{
    const float* x   = (const float*)d_in[0];
    const int*   ei  = (const int*)d_in[1];
    const int*   bat = (const int*)d_in[2];
    const float* W1  = (const float*)d_in[3];
    const float* b1  = (const float*)d_in[4];
    const float* W2  = (const float*)d_in[5];
    const float* b2  = (const float*)d_in[6];
    const float* g1  = (const float*)d_in[7];
    const float* be1 = (const float*)d_in[8];
    const float* rm1 = (const float*)d_in[9];
    const float* rv1 = (const float*)d_in[10];
    const float* g2  = (const float*)d_in[11];
    const float* be2 = (const float*)d_in[12];
    const float* rm2 = (const float*)d_in[13];
    const float* rv2 = (const float*)d_in[14];
    float* outp = (float*)d_out;
    char* ws = (char*)d_ws;

    int*   deg     = (int*)  (ws + 0);         // 200000 B
    int*   cursor  = (int*)  (ws + 200000);    // 200000 B
    int*   cnt     = (int*)  (ws + 400000);    //   8192 B
    int*   offs    = (int*)  (ws + 408192);    // 200016 B (N+1 ints)
    float* dinv    = (float*)(ws + 608208);    // 200000 B
    float* inv_cnt = (float*)(ws + 808208);    //   8192 B
    int*   bsum    = (int*)  (ws + 816400);    //   1024 B
    int*   boff    = (int*)  (ws + 817424);    //   1024 B
    unsigned short* csr_src = (unsigned short*)(ws + 818448);   // 3.2 MB
    unsigned short* Wbf1 = (unsigned short*)(ws + 4018448);     // 46080 B
    unsigned short* Wbf2 = (unsigned short*)(ws + 4064528);     // 46080 B
    unsigned short* Abf  = (unsigned short*)(ws + 4110608);     // 16015360 B (50048 x 160)
    unsigned short* Hb   = (unsigned short*)(ws + 20125968);    // 13613056 B (50048 x 136)
    unsigned short* Y1   = (unsigned short*)(ws + 33739024);    // 16015360 B (50048 x 160)

    hipMemsetAsync(ws, 0, 408192, stream);                       // deg, cursor, cnt
    hipMemsetAsync(d_out, 0, (size_t)out_size * 4, stream);

    const int* row = ei;
    const int* col = ei + N_EDGES;

    int ebl = (N_EDGES + 255) / 256;
    int nbl = (N_NODES + 255) / 256;

    k_count   <<<dim3(ebl), dim3(256), 0, stream>>>(col, bat, deg, cnt);
    k_finalize<<<dim3(nbl), dim3(256), 0, stream>>>(deg, cnt, dinv, inv_cnt);
    k_scan1   <<<dim3(nbl), dim3(256), 0, stream>>>(deg, offs, bsum);
    k_scan2   <<<dim3(1),   dim3(256), 0, stream>>>(bsum, boff, nbl);
    k_scan3   <<<dim3(nbl), dim3(256), 0, stream>>>(offs, boff);
    k_fill    <<<dim3(ebl), dim3(256), 0, stream>>>(row, col, offs, cursor, csr_src);

    k_w2bf<<<dim3(90), dim3(256), 0, stream>>>(W1, Wbf1);
    k_w2bf<<<dim3(90), dim3(256), 0, stream>>>(W2, Wbf2);
    k_x2bf<<<dim3((N_NODES * 80 + 255) / 256), dim3(256), 0, stream>>>(x, (unsigned*)Abf);

    int gbl = N_ROWS / 64;   // 782
    k_gemm_mfma<<<dim3(gbl), dim3(256), 0, stream>>>(Abf, Wbf1, Hb, N_NODES);
    k_agg<false><<<dim3(N_NODES / 4), dim3(256), 0, stream>>>(Hb, offs, csr_src, dinv,
                                                              b1, g1, be1, rm1, rv1,
                                                              Y1, nullptr, nullptr, nullptr);
    k_gemm_mfma<<<dim3(gbl), dim3(256), 0, stream>>>(Y1, Wbf2, Hb, N_NODES);
    k_agg<true><<<dim3(N_NODES / 4), dim3(256), 0, stream>>>(Hb, offs, csr_src, dinv,
                                                             b2, g2, be2, rm2, rv2,
                                                             nullptr, bat, inv_cnt, outp);
}

// Round 6
// 458.995 us; speedup vs baseline: 1.6799x; 1.0558x over previous
//
#include <hip/hip_runtime.h>

#define N_NODES  50000
#define N_ROWS   50048        // padded row count (multiple of 64)
#define N_EDGES  1600000
#define N_GRAPHS 2048
#define DIM      133
#define HSTR     136          // bf16 row stride for gemm-output / agg-input buffers
#define YSTR     160          // bf16 row stride for gemm-input buffers (K padded to 160)
#define EPSV     1e-5f

typedef __attribute__((ext_vector_type(8))) short bf16x8;
typedef __attribute__((ext_vector_type(4))) float f32x4;

// ---- bf16 helpers (raw ushort; bf16 = top 16 bits of fp32) ----
__device__ __forceinline__ float blo(unsigned u) { return __uint_as_float(u << 16); }
__device__ __forceinline__ float bhi(unsigned u) { return __uint_as_float(u & 0xFFFF0000u); }
__device__ __forceinline__ unsigned short f2bf(float x) {
    unsigned v = __float_as_uint(x);
    return (unsigned short)((v + 0x7FFFu + ((v >> 16) & 1u)) >> 16);  // RNE
}
__device__ __forceinline__ unsigned packbf(float a, float b) {
    return (unsigned)f2bf(a) | ((unsigned)f2bf(b) << 16);
}

// ---------------- setup kernels ----------------

__global__ __launch_bounds__(256) void k_count(const int* __restrict__ col,
                                               const int* __restrict__ batch,
                                               int* __restrict__ deg,
                                               int* __restrict__ cnt)
{
    int idx = blockIdx.x * 256 + threadIdx.x;
    if (idx < N_EDGES) atomicAdd(&deg[col[idx]], 1);
    if (idx < N_NODES) atomicAdd(&cnt[batch[idx]], 1);
}

__global__ __launch_bounds__(256) void k_finalize(const int* __restrict__ deg,
                                                  const int* __restrict__ cnt,
                                                  float* __restrict__ dinv,
                                                  float* __restrict__ inv_cnt)
{
    int idx = blockIdx.x * 256 + threadIdx.x;
    if (idx < N_NODES)  dinv[idx]    = rsqrtf((float)deg[idx] + 1.0f); // +1 self loop
    if (idx < N_GRAPHS) inv_cnt[idx] = 1.0f / (float)max(cnt[idx], 1);
}

__global__ __launch_bounds__(256) void k_scan1(const int* __restrict__ deg,
                                               int* __restrict__ offs,
                                               int* __restrict__ bsum)
{
    __shared__ int sd[256];
    int t = threadIdx.x;
    int idx = blockIdx.x * 256 + t;
    int v = (idx < N_NODES) ? deg[idx] : 0;
    sd[t] = v; __syncthreads();
    for (int o = 1; o < 256; o <<= 1) {
        int add = (t >= o) ? sd[t - o] : 0;
        __syncthreads();
        sd[t] += add;
        __syncthreads();
    }
    if (idx < N_NODES) offs[idx] = sd[t] - v;
    if (t == 255) bsum[blockIdx.x] = sd[255];
}

__global__ __launch_bounds__(256) void k_scan2(const int* __restrict__ bsum,
                                               int* __restrict__ boff, int nb)
{
    __shared__ int sd[256];
    int t = threadIdx.x;
    int v = (t < nb) ? bsum[t] : 0;
    sd[t] = v; __syncthreads();
    for (int o = 1; o < 256; o <<= 1) {
        int add = (t >= o) ? sd[t - o] : 0;
        __syncthreads();
        sd[t] += add;
        __syncthreads();
    }
    boff[t] = sd[t] - v;
}

__global__ __launch_bounds__(256) void k_scan3(int* __restrict__ offs,
                                               const int* __restrict__ boff)
{
    int idx = blockIdx.x * 256 + threadIdx.x;
    if (idx < N_NODES)       offs[idx] += boff[blockIdx.x];
    else if (idx == N_NODES) offs[N_NODES] = N_EDGES;
}

// 2-byte CSR record: src node id (fits: 50000 < 65536). dinv looked up in k_agg.
__global__ __launch_bounds__(256) void k_fill(const int* __restrict__ row,
                                              const int* __restrict__ col,
                                              const int* __restrict__ offs,
                                              int* __restrict__ cursor,
                                              unsigned short* __restrict__ csr_src)
{
    int e = blockIdx.x * 256 + threadIdx.x;
    if (e < N_EDGES) {
        int c = col[e];
        int p = offs[c] + atomicAdd(&cursor[c], 1);
        csr_src[p] = (unsigned short)row[e];
    }
}

// ---- pack W (fp32 [133][133], W[k][n]) into MFMA B-fragment layout ----
__global__ __launch_bounds__(256) void k_w2bf(const float* __restrict__ W,
                                              unsigned short* __restrict__ Wbf)
{
    int idx = blockIdx.x * 256 + threadIdx.x;          // 9*5*64*8 = 23040
    if (idx >= 23040) return;
    int j    = idx & 7;
    int lane = (idx >> 3) & 63;
    int kc   = (idx >> 9) % 5;
    int t    = idx / (8 * 64 * 5);
    int k = kc * 32 + (lane >> 4) * 8 + j;
    int n = t * 16 + (lane & 15);
    float v = (k < DIM && n < DIM) ? W[k * DIM + n] : 0.f;
    Wbf[idx] = f2bf(v);
}

// ---- convert x fp32 [N][133] -> bf16 [N][160] with zero K-padding ----
__global__ __launch_bounds__(256) void k_x2bf(const float* __restrict__ x,
                                              unsigned* __restrict__ Abf) // uint = 2 bf16
{
    int idx = blockIdx.x * 256 + threadIdx.x;          // N_NODES * 80
    if (idx >= N_NODES * 80) return;
    int r  = idx / 80;
    int c2 = (idx - r * 80) * 2;
    float a = (c2     < DIM) ? x[(size_t)r * DIM + c2]     : 0.f;
    float b = (c2 + 1 < DIM) ? x[(size_t)r * DIM + c2 + 1] : 0.f;
    Abf[idx] = packbf(a, b);
}

// ---------------- MFMA GEMM: H[M][HSTR](bf16) = A[.][YSTR](bf16) @ W ----------------
__global__ __launch_bounds__(256) void k_gemm_mfma(const unsigned short* __restrict__ A,
                                                   const unsigned short* __restrict__ Wbf,
                                                   unsigned short* __restrict__ H, int M)
{
    int wave = threadIdx.x >> 6, lane = threadIdx.x & 63;
    int quad = lane >> 4, l16 = lane & 15;
    int m = blockIdx.x * 64 + wave * 16 + l16;

    const bf16x8* Arow = (const bf16x8*)(A + (size_t)m * YSTR);
    const bf16x8* Bq   = (const bf16x8*)Wbf;

    f32x4 acc[9] = {};
#pragma unroll
    for (int kc = 0; kc < 5; kc++) {
        bf16x8 af = Arow[kc * 4 + quad];
#pragma unroll
        for (int t = 0; t < 9; t++) {
            bf16x8 bfr = Bq[(t * 5 + kc) * 64 + lane];
            acc[t] = __builtin_amdgcn_mfma_f32_16x16x32_bf16(af, bfr, acc[t], 0, 0, 0);
        }
    }

    int gr0 = blockIdx.x * 64 + wave * 16 + quad * 4;
#pragma unroll
    for (int t = 0; t < 9; t++) {
        int c = t * 16 + l16;
#pragma unroll
        for (int reg = 0; reg < 4; reg++) {
            int gr = gr0 + reg;
            if (gr < M && c < HSTR) {
                float v = (c < DIM) ? acc[t][reg] : 0.f;
                H[(size_t)gr * HSTR + c] = f2bf(v);
            }
        }
    }
}

// ---------------- fused aggregate + bias + ReLU + BN (+ optional mean-pool) ----------------
// 8x-unrolled gather loop: 16 independent loads in flight per wave.

template <bool FINAL>
__global__ __launch_bounds__(256) void k_agg(const unsigned short* __restrict__ h,
                                             const int* __restrict__ offs,
                                             const unsigned short* __restrict__ csr_src,
                                             const float* __restrict__ dinv,
                                             const float* __restrict__ bias,
                                             const float* __restrict__ gam,
                                             const float* __restrict__ bet,
                                             const float* __restrict__ rmean,
                                             const float* __restrict__ rvar,
                                             unsigned short* __restrict__ y,
                                             const int* __restrict__ batch,
                                             const float* __restrict__ inv_cnt,
                                             float* __restrict__ outp)
{
    int node = blockIdx.x * 4 + (threadIdx.x >> 6);
    if (node >= N_NODES) return;
    int lane = threadIdx.x & 63;
    int l2 = lane & 3;

    float di = dinv[node];
    const unsigned* hrow = (const unsigned*)(h + (size_t)node * HSTR);
    unsigned p0 = hrow[lane];        // cols 2*lane, 2*lane+1
    unsigned p1 = hrow[64 + l2];     // cols 128+2*l2 (dup for lanes>=4, discarded)
    float2 a0; a0.x = di * blo(p0); a0.y = di * bhi(p0);   // self-loop term
    float2 a1; a1.x = di * blo(p1); a1.y = di * bhi(p1);

    int s0 = offs[node], s1 = offs[node + 1];
    for (int k0 = s0; k0 < s1; k0 += 64) {
        int nk = min(64, s1 - k0);
        int src = 0; float w = 0.f;
        if (lane < nk) {
            src = csr_src[k0 + lane];
            w   = dinv[src];          // L2-resident 200 KB table
        }
        int j = 0;
        for (; j + 8 <= nk; j += 8) {
            int   ss[8];
            float wv[8];
#pragma unroll
            for (int u = 0; u < 8; u++) {
                ss[u] = __builtin_amdgcn_readfirstlane(__shfl(src, j + u));
                wv[u] = __shfl(w, j + u);
            }
            unsigned q0[8], q1[8];
#pragma unroll
            for (int u = 0; u < 8; u++) {
                const unsigned* r = (const unsigned*)(h + (size_t)ss[u] * HSTR);
                q0[u] = r[lane];
                q1[u] = r[64 + l2];
            }
#pragma unroll
            for (int u = 0; u < 8; u++) {
                a0.x += wv[u] * blo(q0[u]); a0.y += wv[u] * bhi(q0[u]);
                a1.x += wv[u] * blo(q1[u]); a1.y += wv[u] * bhi(q1[u]);
            }
        }
        for (; j < nk; j++) {
            int   s  = __builtin_amdgcn_readfirstlane(__shfl(src, j));
            float ww = __shfl(w, j);
            const unsigned* hr = (const unsigned*)(h + (size_t)s * HSTR);
            unsigned q0 = hr[lane];
            unsigned q1 = hr[64 + l2];
            a0.x += ww * blo(q0); a0.y += ww * bhi(q0);
            a1.x += ww * blo(q1); a1.y += ww * bhi(q1);
        }
    }

    float ic = 0.f; int bg = 0;
    if (FINAL) { bg = batch[node]; ic = inv_cnt[bg]; }

    // main pair: cols 2*lane, 2*lane+1 (both < 128 < DIM)
    {
        int c = 2 * lane;
        float va = di * a0.x + bias[c];
        va = fmaxf(va, 0.f);
        va = (va - rmean[c]) * (gam[c] * rsqrtf(rvar[c] + EPSV)) + bet[c];
        int c1 = c + 1;
        float vb = di * a0.y + bias[c1];
        vb = fmaxf(vb, 0.f);
        vb = (vb - rmean[c1]) * (gam[c1] * rsqrtf(rvar[c1] + EPSV)) + bet[c1];
        if (FINAL) {
            atomicAdd(&outp[(size_t)bg * DIM + c],  va * ic);
            atomicAdd(&outp[(size_t)bg * DIM + c1], vb * ic);
        } else {
            ((unsigned*)(y + (size_t)node * YSTR))[lane] = packbf(va, vb);
        }
    }
    // tail: cols 128..159. lanes 0-3 compute cols 128+2*l2 (masked >=133); lanes 4-15 pad zeros.
    if (lane < 16) {
        float va = 0.f, vb = 0.f;
        if (lane < 4) {
            int c = 128 + 2 * l2;
            if (c < DIM) {
                va = di * a1.x + bias[c];
                va = fmaxf(va, 0.f);
                va = (va - rmean[c]) * (gam[c] * rsqrtf(rvar[c] + EPSV)) + bet[c];
            }
            int c1 = c + 1;
            if (c1 < DIM) {
                vb = di * a1.y + bias[c1];
                vb = fmaxf(vb, 0.f);
                vb = (vb - rmean[c1]) * (gam[c1] * rsqrtf(rvar[c1] + EPSV)) + bet[c1];
            }
            if (FINAL) {
                if (c  < DIM) atomicAdd(&outp[(size_t)bg * DIM + c],  va * ic);
                if (c1 < DIM) atomicAdd(&outp[(size_t)bg * DIM + c1], vb * ic);
            }
        }
        if (!FINAL)
            ((unsigned*)(y + (size_t)node * YSTR))[64 + lane] = packbf(va, vb);
    }
}

// ---------------- launch ----------------

extern "C" void kernel_launch(void* const* d_in, const int* in_sizes, int n_in,
                              void* d_out, int out_size, void* d_ws, size_t ws_size,
                              hipStream_t stream)
{
    const float* x   = (const float*)d_in[0];
    const int*   ei  = (const int*)d_in[1];
    const int*   bat = (const int*)d_in[2];
    const float* W1  = (const float*)d_in[3];
    const float* b1  = (const float*)d_in[4];
    const float* W2  = (const float*)d_in[5];
    const float* b2  = (const float*)d_in[6];
    const float* g1  = (const float*)d_in[7];
    const float* be1 = (const float*)d_in[8];
    const float* rm1 = (const float*)d_in[9];
    const float* rv1 = (const float*)d_in[10];
    const float* g2  = (const float*)d_in[11];
    const float* be2 = (const float*)d_in[12];
    const float* rm2 = (const float*)d_in[13];
    const float* rv2 = (const float*)d_in[14];
    float* outp = (float*)d_out;
    char* ws = (char*)d_ws;

    int*   deg     = (int*)  (ws + 0);         // 200000 B
    int*   cursor  = (int*)  (ws + 200000);    // 200000 B
    int*   cnt     = (int*)  (ws + 400000);    //   8192 B
    int*   offs    = (int*)  (ws + 408192);    // 200016 B (N+1 ints)
    float* dinv    = (float*)(ws + 608208);    // 200000 B
    float* inv_cnt = (float*)(ws + 808208);    //   8192 B
    int*   bsum    = (int*)  (ws + 816400);    //   1024 B
    int*   boff    = (int*)  (ws + 817424);    //   1024 B
    unsigned short* csr_src = (unsigned short*)(ws + 818448);   // 3.2 MB
    unsigned short* Wbf1 = (unsigned short*)(ws + 4018448);     // 46080 B
    unsigned short* Wbf2 = (unsigned short*)(ws + 4064528);     // 46080 B
    unsigned short* Abf  = (unsigned short*)(ws + 4110608);     // 16015360 B (50048 x 160)
    unsigned short* Hb   = (unsigned short*)(ws + 20125968);    // 13613056 B (50048 x 136)
    unsigned short* Y1   = (unsigned short*)(ws + 33739024);    // 16015360 B (50048 x 160)

    hipMemsetAsync(ws, 0, 408192, stream);                       // deg, cursor, cnt
    hipMemsetAsync(d_out, 0, (size_t)out_size * 4, stream);

    const int* row = ei;
    const int* col = ei + N_EDGES;

    int ebl = (N_EDGES + 255) / 256;
    int nbl = (N_NODES + 255) / 256;

    k_count   <<<dim3(ebl), dim3(256), 0, stream>>>(col, bat, deg, cnt);
    k_finalize<<<dim3(nbl), dim3(256), 0, stream>>>(deg, cnt, dinv, inv_cnt);
    k_scan1   <<<dim3(nbl), dim3(256), 0, stream>>>(deg, offs, bsum);
    k_scan2   <<<dim3(1),   dim3(256), 0, stream>>>(bsum, boff, nbl);
    k_scan3   <<<dim3(nbl), dim3(256), 0, stream>>>(offs, boff);
    k_fill    <<<dim3(ebl), dim3(256), 0, stream>>>(row, col, offs, cursor, csr_src);

    k_w2bf<<<dim3(90), dim3(256), 0, stream>>>(W1, Wbf1);
    k_w2bf<<<dim3(90), dim3(256), 0, stream>>>(W2, Wbf2);
    k_x2bf<<<dim3((N_NODES * 80 + 255) / 256), dim3(256), 0, stream>>>(x, (unsigned*)Abf);

    int gbl = N_ROWS / 64;   // 782
    k_gemm_mfma<<<dim3(gbl), dim3(256), 0, stream>>>(Abf, Wbf1, Hb, N_NODES);
    k_agg<false><<<dim3(N_NODES / 4), dim3(256), 0, stream>>>(Hb, offs, csr_src, dinv,
                                                              b1, g1, be1, rm1, rv1,
                                                              Y1, nullptr, nullptr, nullptr);
    k_gemm_mfma<<<dim3(gbl), dim3(256), 0, stream>>>(Y1, Wbf2, Hb, N_NODES);
    k_agg<true><<<dim3(N_NODES / 4), dim3(256), 0, stream>>>(Hb, offs, csr_src, dinv,
                                                             b2, g2, be2, rm2, rv2,
                                                             nullptr, bat, inv_cnt, outp);
}